// Round 1
// baseline (75.331 us; speedup 1.0000x reference)
//
#include <hip/hip_runtime.h>

#define NROWS 8192
#define DDIM 64
#define HDIM 256
#define HPAD 264   // bf16 elements per h_lds row (pad 256 -> 264 to spread banks)

using bf16x8 = __attribute__((ext_vector_type(8))) short;
using f32x4  = __attribute__((ext_vector_type(4))) float;

__device__ __forceinline__ unsigned short f2bf(float x) {
    unsigned u = __float_as_uint(x);
    u += 0x7FFFu + ((u >> 16) & 1u);   // round-to-nearest-even
    return (unsigned short)(u >> 16);
}

__device__ __forceinline__ float fast_tanh(float x) {
    // tanh(x) = 1 - 2/(exp(2x)+1); exp overflow -> rcp(inf)=0 -> 1; underflow -> -1
    float e = __expf(2.0f * x);
    return 1.0f - 2.0f * __builtin_amdgcn_rcpf(e + 1.0f);
}

// ---------------- prep: W1^T, W2^T to bf16 in ws; c = b1 + t*wt; s_m = sum_k W1[k,m]W2[m,k]
__global__ void prep_kernel(const float* __restrict__ t,
                            const float* __restrict__ W1,
                            const float* __restrict__ b1,
                            const float* __restrict__ wt,
                            const float* __restrict__ W2,
                            unsigned short* __restrict__ W1t,   // [256][64]
                            unsigned short* __restrict__ W2t,   // [64][256]
                            float* __restrict__ Cb,             // [256]
                            float* __restrict__ Sv) {           // [256]
    int gid = blockIdx.x * 256 + threadIdx.x;
    if (blockIdx.x < 64) {
        // W1t[m][k] = bf16(W1[k][m]);  W1 is [64][256] row-major
        int m = gid >> 6, k = gid & 63;
        W1t[gid] = f2bf(W1[k * HDIM + m]);
    } else if (blockIdx.x < 128) {
        int i = gid - 16384;            // [0, 16384)
        int n = i >> 8, k = i & 255;    // W2t[n][k] = bf16(W2[k][n]); W2 is [256][64]
        W2t[i] = f2bf(W2[k * DDIM + n]);
    } else {
        int m = threadIdx.x;            // 0..255
        Cb[m] = b1[m] + t[0] * wt[m];
        float s = 0.f;
        #pragma unroll
        for (int k = 0; k < DDIM; ++k) s += W1[k * HDIM + m] * W2[m * DDIM + k];
        Sv[m] = s;
    }
}

// ---------------- main: 16 rows per block, 256 threads (4 waves)
__global__ __launch_bounds__(256)
void ode_main(const float* __restrict__ y,
              const unsigned short* __restrict__ W1t,
              const unsigned short* __restrict__ W2t,
              const float* __restrict__ Cb,
              const float* __restrict__ Sv,
              const float* __restrict__ b2,
              float* __restrict__ out) {
    const int tid  = threadIdx.x;
    const int w    = tid >> 6;     // wave 0..3 -> H columns [w*64, w*64+64)
    const int lane = tid & 63;
    const int l16  = lane & 15;
    const int quad = lane >> 4;
    const int row0 = blockIdx.x * 16;

    __shared__ __align__(16) unsigned short h_lds[16 * HPAD];  // h in bf16, [row][m] padded
    __shared__ float dvp[64];                                  // per-wave div partials [w][row]

    // ---- A-frags from y (fp32 global -> bf16 regs). A[m=l16(row)][k=quad*8+j]
    bf16x8 afr[2];
    const float* yrow = y + (size_t)(row0 + l16) * DDIM;
    #pragma unroll
    for (int ks = 0; ks < 2; ++ks) {
        const float4 f0 = *(const float4*)(yrow + ks * 32 + quad * 8);
        const float4 f1 = *(const float4*)(yrow + ks * 32 + quad * 8 + 4);
        bf16x8 a;
        a[0] = (short)f2bf(f0.x); a[1] = (short)f2bf(f0.y);
        a[2] = (short)f2bf(f0.z); a[3] = (short)f2bf(f0.w);
        a[4] = (short)f2bf(f1.x); a[5] = (short)f2bf(f1.y);
        a[6] = (short)f2bf(f1.z); a[7] = (short)f2bf(f1.w);
        afr[ks] = a;
    }

    // ---- phase 1: z = y @ W1  (wave w covers 4 column tiles of 16)
    f32x4 acc[4];
    #pragma unroll
    for (int ct = 0; ct < 4; ++ct) acc[ct] = (f32x4){0.f, 0.f, 0.f, 0.f};

    #pragma unroll
    for (int ct = 0; ct < 4; ++ct) {
        const int m = w * 64 + ct * 16 + l16;     // H column for this lane's B frag
        #pragma unroll
        for (int ks = 0; ks < 2; ++ks) {
            bf16x8 b = *(const bf16x8*)(W1t + m * DDIM + ks * 32 + quad * 8);
            acc[ct] = __builtin_amdgcn_mfma_f32_16x16x32_bf16(afr[ks], b, acc[ct], 0, 0, 0);
        }
    }

    // ---- bias + tanh + divergence partials; store h (bf16) to LDS in [row][m]
    float dv[4] = {0.f, 0.f, 0.f, 0.f};
    #pragma unroll
    for (int ct = 0; ct < 4; ++ct) {
        const int m = w * 64 + ct * 16 + l16;
        const float cb = Cb[m];
        const float sv = Sv[m];
        #pragma unroll
        for (int r = 0; r < 4; ++r) {             // C layout: col=l16, row=quad*4+r
            float z = acc[ct][r] + cb;
            float h = fast_tanh(z);
            dv[r] += (1.f - h * h) * sv;
            h_lds[(quad * 4 + r) * HPAD + m] = f2bf(h);
        }
    }
    // reduce dv over the 16 lanes of this quad group (same rows, different cols)
    #pragma unroll
    for (int off = 8; off; off >>= 1) {
        #pragma unroll
        for (int r = 0; r < 4; ++r) dv[r] += __shfl_down(dv[r], off, 16);
    }
    if (l16 == 0) {
        #pragma unroll
        for (int r = 0; r < 4; ++r) dvp[w * 16 + quad * 4 + r] = dv[r];
    }
    __syncthreads();

    // ---- phase 2: dy = h @ W2 (wave w computes output cols [w*16, w*16+16))
    f32x4 acc2 = (f32x4){0.f, 0.f, 0.f, 0.f};
    const int n = w * 16 + l16;                   // output column 0..63
    #pragma unroll
    for (int ks = 0; ks < 8; ++ks) {
        bf16x8 a = *(const bf16x8*)(&h_lds[l16 * HPAD + ks * 32 + quad * 8]);
        bf16x8 b = *(const bf16x8*)(W2t + n * HDIM + ks * 32 + quad * 8);
        acc2 = __builtin_amdgcn_mfma_f32_16x16x32_bf16(a, b, acc2, 0, 0, 0);
    }
    const float b2v = b2[n];
    #pragma unroll
    for (int r = 0; r < 4; ++r) {
        const int row = quad * 4 + r;
        out[(size_t)(row0 + row) * (DDIM + 1) + n] = acc2[r] + b2v;
    }

    // ---- divergence column (col 64): sum the 4 wave partials per row
    if (w == 0 && lane < 16) {
        float s = dvp[lane] + dvp[16 + lane] + dvp[32 + lane] + dvp[48 + lane];
        out[(size_t)(row0 + lane) * (DDIM + 1) + DDIM] = -s;
    }
}

extern "C" void kernel_launch(void* const* d_in, const int* in_sizes, int n_in,
                              void* d_out, int out_size, void* d_ws, size_t ws_size,
                              hipStream_t stream) {
    const float* t  = (const float*)d_in[0];
    const float* y  = (const float*)d_in[1];
    const float* W1 = (const float*)d_in[2];
    const float* b1 = (const float*)d_in[3];
    const float* wt = (const float*)d_in[4];
    const float* W2 = (const float*)d_in[5];
    const float* b2 = (const float*)d_in[6];
    float* out = (float*)d_out;

    unsigned short* W1t = (unsigned short*)d_ws;                       // 32768 B
    unsigned short* W2t = (unsigned short*)((char*)d_ws + 32768);      // 32768 B
    float* Cb = (float*)((char*)d_ws + 65536);                         // 1024 B
    float* Sv = (float*)((char*)d_ws + 66560);                         // 1024 B

    prep_kernel<<<129, 256, 0, stream>>>(t, W1, b1, wt, W2, W1t, W2t, Cb, Sv);
    ode_main<<<NROWS / 16, 256, 0, stream>>>(y, W1t, W2t, Cb, Sv, b2, out);
}